// Round 1
// baseline (207.977 us; speedup 1.0000x reference)
//
#include <hip/hip_runtime.h>
#include <hip/hip_bf16.h>
#include <stdint.h>

typedef __hip_bfloat16 bf16;
typedef __attribute__((ext_vector_type(8))) short bf16x8;
typedef __attribute__((ext_vector_type(4))) float f32x4;
typedef __attribute__((ext_vector_type(8))) unsigned short u16x8;
typedef __attribute__((ext_vector_type(4))) unsigned short u16x4;

#define SLEN 2048
#define ED   1024
#define NB   4

static __device__ __forceinline__ unsigned short f2bf(float f) {
    return __builtin_bit_cast(unsigned short, __float2bfloat16(f));
}

// Stage a 128x32 bf16 tile (8 KB) from global (leading dim ld, elements) into
// linear LDS via async global_load_lds, width 16B. 256 threads, 2 issues/wave.
static __device__ __forceinline__ void stage128x32(const bf16* __restrict__ g, int ld,
                                                   bf16* lds, int tid)
{
    int wave = tid >> 6, lane = tid & 63;
#pragma unroll
    for (int i = 0; i < 2; ++i) {
        int chunk = (wave * 2 + i) * 64 + lane;   // 16B-unit index 0..511
        int e = chunk * 8;                        // element offset
        int r = e >> 5, c = e & 31;
        // LDS dest: wave-uniform base; HW adds lane*16 (m104 semantics)
        __builtin_amdgcn_global_load_lds(
            (const __attribute__((address_space(1))) uint32_t*)(g + (size_t)r * ld + c),
            (__attribute__((address_space(3))) uint32_t*)(lds + (size_t)(wave * 2 + i) * 512),
            16, 0, 0);
    }
}

// One BK=32 K-step: 4+4 fragment loads, 16 MFMAs. Wave (wm,wn) owns a 64x64 subtile.
static __device__ __forceinline__ void mma_step(const bf16* As, const bf16* Bs,
                                                f32x4 acc[4][4], int lane, int wm, int wn)
{
    int lr = lane & 15;
    int kg = (lane >> 4) * 8;
    bf16x8 a[4], b[4];
#pragma unroll
    for (int m = 0; m < 4; ++m)
        a[m] = *(const bf16x8*)(As + (wm * 64 + m * 16 + lr) * 32 + kg);
#pragma unroll
    for (int n = 0; n < 4; ++n)
        b[n] = *(const bf16x8*)(Bs + (wn * 64 + n * 16 + lr) * 32 + kg);
#pragma unroll
    for (int m = 0; m < 4; ++m)
#pragma unroll
        for (int n = 0; n < 4; ++n)
            acc[m][n] = __builtin_amdgcn_mfma_f32_16x16x32_bf16(a[m], b[n], acc[m][n], 0, 0, 0);
}

// ---------------- convert fp32 -> bf16 (x and the 3 weights) ----------------
__global__ __launch_bounds__(256) void convert_to_bf16(
    const float* __restrict__ x, const float* __restrict__ wq,
    const float* __restrict__ wk, const float* __restrict__ wv,
    bf16* __restrict__ xb, bf16* __restrict__ wqb,
    bf16* __restrict__ wkb, bf16* __restrict__ wvb)
{
    long g = (long)blockIdx.x * 256 + threadIdx.x;   // each thread: 8 elements
    const float* src; bf16* dst; long o;
    if (g < 1048576) { src = x; dst = xb; o = g * 8; }
    else {
        long g2 = g - 1048576;
        int w = (int)(g2 >> 17);
        o = (g2 & 131071) * 8;
        src = (w == 0) ? wq : (w == 1) ? wk : wv;
        dst = (w == 0) ? wqb : (w == 1) ? wkb : wvb;
    }
    float4 v0 = *(const float4*)(src + o);
    float4 v1 = *(const float4*)(src + o + 4);
    u16x8 r;
    r[0] = f2bf(v0.x); r[1] = f2bf(v0.y); r[2] = f2bf(v0.z); r[3] = f2bf(v0.w);
    r[4] = f2bf(v1.x); r[5] = f2bf(v1.y); r[6] = f2bf(v1.z); r[7] = f2bf(v1.w);
    *(u16x8*)(dst + o) = r;
}

// ---------------- QKV projection GEMM: C[8192,1024] = xb @ W^T ----------------
// z=0 -> Q (natural layout), z=1 -> K (natural), z=2 -> V written transposed per batch
__global__ __launch_bounds__(256) void qkv_gemm(
    const bf16* __restrict__ xb, const bf16* __restrict__ wq,
    const bf16* __restrict__ wk, const bf16* __restrict__ wv,
    bf16* __restrict__ Qb, bf16* __restrict__ Kb, bf16* __restrict__ Vt)
{
    __shared__ __align__(16) bf16 As[128 * 32];
    __shared__ __align__(16) bf16 Bs[128 * 32];
    int tid = threadIdx.x, lane = tid & 63, wave = tid >> 6;
    int wm = wave >> 1, wn = wave & 1;
    int tm = blockIdx.x, tn = blockIdx.y, which = blockIdx.z;
    const bf16* W = (which == 0) ? wq : (which == 1) ? wk : wv;
    const bf16* Ab = xb + (size_t)tm * 128 * ED;
    const bf16* Bb = W + (size_t)tn * 128 * ED;
    f32x4 acc[4][4] = {};
    for (int kt = 0; kt < ED / 32; ++kt) {
        __syncthreads();
        stage128x32(Ab + kt * 32, ED, As, tid);
        stage128x32(Bb + kt * 32, ED, Bs, tid);
        __syncthreads();
        mma_step(As, Bs, acc, lane, wm, wn);
    }
    int rl = (lane >> 4) * 4, cl = lane & 15;
    int rbase = tm * 128 + wm * 64, cbase = tn * 128 + wn * 64;
    if (which < 2) {
        bf16* C = (which == 0) ? Qb : Kb;
#pragma unroll
        for (int m = 0; m < 4; ++m)
#pragma unroll
            for (int j = 0; j < 4; ++j) {
                int r = rbase + m * 16 + rl + j;
#pragma unroll
                for (int n = 0; n < 4; ++n) {
                    int c = cbase + n * 16 + cl;
                    C[(size_t)r * ED + c] = __float2bfloat16(acc[m][n][j]);
                }
            }
    } else {
        // Vt[b][d][s] = V[b][s][d]
#pragma unroll
        for (int m = 0; m < 4; ++m)
#pragma unroll
            for (int j = 0; j < 4; ++j) {
                int r = rbase + m * 16 + rl + j;
                int b = r >> 11, si = r & 2047;
#pragma unroll
                for (int n = 0; n < 4; ++n) {
                    int c = cbase + n * 16 + cl;
                    Vt[((size_t)b * ED + c) * SLEN + si] = __float2bfloat16(acc[m][n][j]);
                }
            }
    }
}

// ---------------- scores = Q @ K^T / 32, lower-triangular tiles only ----------------
// Sc row stride = 2048 fp32 (8 KB); masked region never written (never read either).
__global__ __launch_bounds__(256) void qk_gemm(
    const bf16* __restrict__ Qb, const bf16* __restrict__ Kb, float* __restrict__ Sc)
{
    int tqx = blockIdx.x, tky = blockIdx.y, b = blockIdx.z;
    if (tky > tqx) return;   // fully masked tile
    __shared__ __align__(16) bf16 As[128 * 32];
    __shared__ __align__(16) bf16 Bs[128 * 32];
    int tid = threadIdx.x, lane = tid & 63, wave = tid >> 6;
    int wm = wave >> 1, wn = wave & 1;
    const bf16* Ab = Qb + (size_t)b * SLEN * ED + (size_t)tqx * 128 * ED;
    const bf16* Bb = Kb + (size_t)b * SLEN * ED + (size_t)tky * 128 * ED;
    f32x4 acc[4][4] = {};
    for (int kt = 0; kt < ED / 32; ++kt) {
        __syncthreads();
        stage128x32(Ab + kt * 32, ED, As, tid);
        stage128x32(Bb + kt * 32, ED, Bs, tid);
        __syncthreads();
        mma_step(As, Bs, acc, lane, wm, wn);
    }
    float* Sb = Sc + (size_t)b * SLEN * SLEN;
    int rl = (lane >> 4) * 4, cl = lane & 15;
    int rbase = tqx * 128 + wm * 64, cbase = tky * 128 + wn * 64;
#pragma unroll
    for (int m = 0; m < 4; ++m)
#pragma unroll
        for (int j = 0; j < 4; ++j) {
            int r = rbase + m * 16 + rl + j;
#pragma unroll
            for (int n = 0; n < 4; ++n) {
                int c = cbase + n * 16 + cl;
                Sb[(size_t)r * SLEN + c] = acc[m][n][j] * 0.03125f;
            }
        }
}

// ---------------- causal row softmax; writes P (bf16) in-place over the score row ----
// P row q lives at (bf16*)(score row q) -> P leading dim = 4096 bf16 elements.
__global__ __launch_bounds__(256) void softmax_rows(float* __restrict__ Sc)
{
    int q = blockIdx.x, b = blockIdx.y, tid = threadIdx.x;
    float* row = Sc + ((size_t)b * SLEN + q) * SLEN;
    int lane = tid & 63, wave = tid >> 6;
    __shared__ float red[4];

    float vals[8];
    float lmax = -3.0e38f;
#pragma unroll
    for (int r = 0; r < 2; ++r) {
        int i4 = tid + r * 256;
        float4 v = *(const float4*)(row + i4 * 4);
        vals[r * 4 + 0] = v.x; vals[r * 4 + 1] = v.y;
        vals[r * 4 + 2] = v.z; vals[r * 4 + 3] = v.w;
#pragma unroll
        for (int e = 0; e < 4; ++e) {
            int k = i4 * 4 + e;
            if (k <= q) lmax = fmaxf(lmax, vals[r * 4 + e]);
        }
    }
    // block max
#pragma unroll
    for (int o = 32; o > 0; o >>= 1) lmax = fmaxf(lmax, __shfl_xor(lmax, o));
    if (lane == 0) red[wave] = lmax;
    __syncthreads();
    float m = fmaxf(fmaxf(red[0], red[1]), fmaxf(red[2], red[3]));
    __syncthreads();
    // block sum of exp
    float lsum = 0.f;
#pragma unroll
    for (int r = 0; r < 2; ++r)
#pragma unroll
        for (int e = 0; e < 4; ++e) {
            int k = (tid + r * 256) * 4 + e;
            if (k <= q) lsum += __expf(vals[r * 4 + e] - m);
        }
#pragma unroll
    for (int o = 32; o > 0; o >>= 1) lsum += __shfl_xor(lsum, o);
    if (lane == 0) red[wave] = lsum;
    __syncthreads();
    float inv = 1.0f / (red[0] + red[1] + red[2] + red[3]);
    // write P (bf16) over the head of this row; all fp32 reads completed pre-barrier
    unsigned short* prow = (unsigned short*)row;
#pragma unroll
    for (int r = 0; r < 2; ++r) {
        int i4 = tid + r * 256;
        u16x4 o4;
#pragma unroll
        for (int e = 0; e < 4; ++e) {
            int k = i4 * 4 + e;
            float p = (k <= q) ? __expf(vals[r * 4 + e] - m) * inv : 0.0f;
            o4[e] = f2bf(p);
        }
        *(u16x4*)(prow + i4 * 4) = o4;
    }
}

// ---------------- O = P @ V  (P: bf16, ld 4096; Vt: [b][d][s]) ----------------
__global__ __launch_bounds__(256) void pv_gemm(
    const bf16* __restrict__ P, const bf16* __restrict__ Vt, float* __restrict__ O)
{
    int tq = blockIdx.x, td = blockIdx.y, b = blockIdx.z;
    __shared__ __align__(16) bf16 As[128 * 32];
    __shared__ __align__(16) bf16 Bs[128 * 32];
    int tid = threadIdx.x, lane = tid & 63, wave = tid >> 6;
    int wm = wave >> 1, wn = wave & 1;
    const bf16* Ab = P + (size_t)b * SLEN * 4096 + (size_t)tq * 128 * 4096;
    const bf16* Bb = Vt + (size_t)b * ED * SLEN + (size_t)td * 128 * SLEN;
    f32x4 acc[4][4] = {};
    int nk = (tq + 1) * 4;   // causal bound: k < (tq+1)*128
    for (int kt = 0; kt < nk; ++kt) {
        __syncthreads();
        stage128x32(Ab + kt * 32, 4096, As, tid);
        stage128x32(Bb + kt * 32, SLEN, Bs, tid);
        __syncthreads();
        mma_step(As, Bs, acc, lane, wm, wn);
    }
    int rl = (lane >> 4) * 4, cl = lane & 15;
    int rbase = tq * 128 + wm * 64, cbase = td * 128 + wn * 64;
    float* Ob = O + (size_t)b * SLEN * ED;
#pragma unroll
    for (int m = 0; m < 4; ++m)
#pragma unroll
        for (int j = 0; j < 4; ++j) {
            int r = rbase + m * 16 + rl + j;
#pragma unroll
            for (int n = 0; n < 4; ++n) {
                int c = cbase + n * 16 + cl;
                Ob[(size_t)r * ED + c] = acc[m][n][j];
            }
        }
}

extern "C" void kernel_launch(void* const* d_in, const int* in_sizes, int n_in,
                              void* d_out, int out_size, void* d_ws, size_t ws_size,
                              hipStream_t stream)
{
    const float* x  = (const float*)d_in[0];
    const float* wq = (const float*)d_in[1];
    const float* wk = (const float*)d_in[2];
    const float* wv = (const float*)d_in[3];
    float* out = (float*)d_out;

    char* ws = (char*)d_ws;
    bf16* xb  = (bf16*)(ws);                       // 16 MB
    bf16* wqb = (bf16*)(ws + 16777216);            // 2 MB
    bf16* wkb = (bf16*)(ws + 18874368);            // 2 MB
    bf16* wvb = (bf16*)(ws + 20971520);            // 2 MB
    bf16* Qb  = (bf16*)(ws + 23068672);            // 16 MB
    bf16* Kb  = (bf16*)(ws + 39845888);            // 16 MB
    bf16* Vt  = (bf16*)(ws + 56623104);            // 16 MB
    float* Sc = (float*)(ws + 73400320);           // 64 MB (P bf16 aliases this)

    convert_to_bf16<<<5632, 256, 0, stream>>>(x, wq, wk, wv, xb, wqb, wkb, wvb);
    qkv_gemm<<<dim3(64, 8, 3), 256, 0, stream>>>(xb, wqb, wkb, wvb, Qb, Kb, Vt);
    qk_gemm<<<dim3(16, 16, NB), 256, 0, stream>>>(Qb, Kb, Sc);
    softmax_rows<<<dim3(SLEN, NB), 256, 0, stream>>>(Sc);
    pv_gemm<<<dim3(16, 8, NB), 256, 0, stream>>>((const bf16*)Sc, Vt, out);
}

// Round 2
// 194.239 us; speedup vs baseline: 1.0707x; 1.0707x over previous
//
#include <hip/hip_runtime.h>
#include <hip/hip_bf16.h>
#include <stdint.h>

typedef __hip_bfloat16 bf16;
typedef __attribute__((ext_vector_type(8))) short bf16x8;
typedef __attribute__((ext_vector_type(4))) float f32x4;
typedef __attribute__((ext_vector_type(8))) unsigned short u16x8;
typedef __attribute__((ext_vector_type(4))) unsigned short u16x4;

#define SLEN 2048
#define ED   1024
#define NB   4

static __device__ __forceinline__ unsigned short f2bf(float f) {
    return __builtin_bit_cast(unsigned short, __float2bfloat16(f));
}

// ============================================================================
// Ring-4 pipelined GEMM core. BK=32, 512 threads (8 waves, 2M x 4N).
// MFR = m-fragments per wave (8 -> BM=256, 4 -> BM=128). BN fixed 256.
// LDS: 4 K-tile slots; stage-ahead 3 tiles; counted vmcnt(2G) at tile end.
// T2 swizzle: 16B chunk c within a 64B row stored/read at c ^ (row&3).
// Safety: slot (T+3)&3 rewritten only after barrier ending compute of T-1;
// per-wave vmcnt(2G) guarantees tile T+1 fully landed before its reads.
// ============================================================================
template<int MFR>
__device__ __forceinline__ void ring4_gemm(
    const char* aRow0, int ldaB,   // global A tile: row 0 ptr, byte stride
    const char* bRow0, int ldbB,   // global B tile (n-major, k contiguous)
    int nkt, char* smem, int tid, f32x4 acc[MFR][4])
{
    constexpr int NGA = MFR / 4;          // 8KB A-groups per tile
    constexpr int NG  = NGA + 2;          // + 2 B-groups (BN=256)
    constexpr int SLOTB = NG * 8192;
    const int lane = tid & 63, wave = tid >> 6;
    const int wm = wave >> 2, wn = wave & 3;

    // per-thread stage sources (pre-swizzled global addresses) + uniform LDS offs
    const char* src[NG];
    int uoff[NG];
#pragma unroll
    for (int g = 0; g < NG; ++g) {
        const bool isA = (g < NGA);
        const int rid = isA ? (g * 512 + tid) : ((g - NGA) * 512 + tid);
        const int p = rid * 16;
        const int row = p >> 6, c = (p >> 4) & 3;
        const int cs = c ^ (row & 3);                    // inverse swizzle (involution)
        src[g] = (isA ? aRow0 + (size_t)row * ldaB
                      : bRow0 + (size_t)row * ldbB) + cs * 16;
        uoff[g] = (isA ? 0 : NGA * 8192) + ((rid >> 6) << 10);  // wave-uniform
    }

    auto STAGE = [&](int slot) {
        char* sb = smem + slot * SLOTB;
#pragma unroll
        for (int g = 0; g < NG; ++g) {
            __builtin_amdgcn_global_load_lds(
                (const __attribute__((address_space(1))) uint32_t*)(src[g]),
                (__attribute__((address_space(3))) uint32_t*)(sb + uoff[g]),
                16, 0, 0);
            src[g] += 64;                                // next K-tile (32 bf16)
        }
    };

    STAGE(0); STAGE(1); STAGE(2);                        // callers ensure nkt >= 3
    if constexpr (MFR == 8) asm volatile("s_waitcnt vmcnt(8)" ::: "memory");
    else                    asm volatile("s_waitcnt vmcnt(6)" ::: "memory");
    __builtin_amdgcn_sched_barrier(0);
    __builtin_amdgcn_s_barrier();

    const int fr = lane & 15, kc = lane >> 4;
    for (int T = 0; T < nkt; ++T) {
        const char* sb = smem + (T & 3) * SLOTB;
        const bf16* As = (const bf16*)sb;
        const bf16* Bs = (const bf16*)(sb + NGA * 8192);

        if (T + 3 < nkt) STAGE((T + 3) & 3);             // writes slot (T-1)&3: free
        __builtin_amdgcn_sched_barrier(0);               // pin issue-early

        bf16x8 b[4];
#pragma unroll
        for (int nf = 0; nf < 4; ++nf) {
            int row = wn * 64 + nf * 16 + fr;
            b[nf] = *(const bf16x8*)(Bs + row * 32 + ((kc ^ (row & 3)) * 8));
        }
#pragma unroll
        for (int mq = 0; mq < MFR / 4; ++mq) {
            bf16x8 a[4];
#pragma unroll
            for (int i = 0; i < 4; ++i) {
                int row = wm * (MFR * 16) + (mq * 4 + i) * 16 + fr;
                a[i] = *(const bf16x8*)(As + row * 32 + ((kc ^ (row & 3)) * 8));
            }
            __builtin_amdgcn_s_setprio(1);
#pragma unroll
            for (int i = 0; i < 4; ++i)
#pragma unroll
                for (int nf = 0; nf < 4; ++nf)
                    acc[mq * 4 + i][nf] = __builtin_amdgcn_mfma_f32_16x16x32_bf16(
                        a[i], b[nf], acc[mq * 4 + i][nf], 0, 0, 0);
            __builtin_amdgcn_s_setprio(0);
            if (MFR == 8 && mq == 0) __builtin_amdgcn_s_barrier();  // phase split
        }
        if constexpr (MFR == 8) asm volatile("s_waitcnt vmcnt(8)" ::: "memory");
        else                    asm volatile("s_waitcnt vmcnt(6)" ::: "memory");
        __builtin_amdgcn_sched_barrier(0);
        __builtin_amdgcn_s_barrier();
    }
}

// ---------------- convert fp32 -> bf16 (x and the 3 weights) ----------------
__global__ __launch_bounds__(256) void convert_to_bf16(
    const float* __restrict__ x, const float* __restrict__ wq,
    const float* __restrict__ wk, const float* __restrict__ wv,
    bf16* __restrict__ xb, bf16* __restrict__ wqb,
    bf16* __restrict__ wkb, bf16* __restrict__ wvb)
{
    long g = (long)blockIdx.x * 256 + threadIdx.x;   // each thread: 8 elements
    const float* src; bf16* dst; long o;
    if (g < 1048576) { src = x; dst = xb; o = g * 8; }
    else {
        long g2 = g - 1048576;
        int w = (int)(g2 >> 17);
        o = (g2 & 131071) * 8;
        src = (w == 0) ? wq : (w == 1) ? wk : wv;
        dst = (w == 0) ? wqb : (w == 1) ? wkb : wvb;
    }
    float4 v0 = *(const float4*)(src + o);
    float4 v1 = *(const float4*)(src + o + 4);
    u16x8 r;
    r[0] = f2bf(v0.x); r[1] = f2bf(v0.y); r[2] = f2bf(v0.z); r[3] = f2bf(v0.w);
    r[4] = f2bf(v1.x); r[5] = f2bf(v1.y); r[6] = f2bf(v1.z); r[7] = f2bf(v1.w);
    *(u16x8*)(dst + o) = r;
}

// ---------------- fused QKV: [8192,3072] = xb @ [wq;wk;wv]^T, 256^2 tiles ----
__global__ __launch_bounds__(512, 2) void qkv256(
    const bf16* __restrict__ xb, const bf16* __restrict__ wqb,
    const bf16* __restrict__ wkb, const bf16* __restrict__ wvb,
    bf16* __restrict__ Qb, bf16* __restrict__ Kb, bf16* __restrict__ Vt)
{
    extern __shared__ char smem[];
    int bid = blockIdx.x;
    int swz = (bid & 7) * 48 + (bid >> 3);     // XCD swizzle, 384 = 8*48
    int tm = swz / 12, tn = swz % 12;
    int tid = threadIdx.x;
    const bf16* W = (tn < 4) ? wqb : (tn < 8) ? wkb : wvb;
    int tnl = tn & 3;
    f32x4 acc[8][4] = {};
    ring4_gemm<8>((const char*)(xb + (size_t)tm * 256 * ED), ED * 2,
                  (const char*)(W + (size_t)tnl * 256 * ED), ED * 2,
                  32, smem, tid, acc);

    int lane = tid & 63, wave = tid >> 6, wm = wave >> 2, wn = wave & 3;
    int rl = (lane >> 4) * 4, cl = lane & 15;
    if (tn < 8) {
        bf16* C = (tn < 4) ? Qb : Kb;
#pragma unroll
        for (int mf = 0; mf < 8; ++mf)
#pragma unroll
            for (int j = 0; j < 4; ++j) {
                int r = tm * 256 + wm * 128 + mf * 16 + rl + j;
#pragma unroll
                for (int nf = 0; nf < 4; ++nf) {
                    int n = tn * 256 + wn * 64 + nf * 16 + cl;
                    C[(size_t)r * ED + (n & 1023)] = __float2bfloat16(acc[mf][nf][j]);
                }
            }
    } else {
#pragma unroll
        for (int mf = 0; mf < 8; ++mf)
#pragma unroll
            for (int j = 0; j < 4; ++j) {
                int r = tm * 256 + wm * 128 + mf * 16 + rl + j;
                int bb = r >> 11, s = r & 2047;
#pragma unroll
                for (int nf = 0; nf < 4; ++nf) {
                    int d = (tn * 256 + wn * 64 + nf * 16 + cl) & 1023;
                    Vt[(((size_t)bb << 10) + d) * SLEN + s] = __float2bfloat16(acc[mf][nf][j]);
                }
            }
    }
}

// ---------------- scores = Q @ K^T / 32, lower-tri 256^2 tiles only ----------
__global__ __launch_bounds__(512, 2) void qk256(
    const bf16* __restrict__ Qb, const bf16* __restrict__ Kb, float* __restrict__ Sc)
{
    extern __shared__ char smem[];
    int t = blockIdx.x, b = blockIdx.y, tid = threadIdx.x;
    int ti = 0;
    while ((ti + 1) * (ti + 2) / 2 <= t) ++ti;   // triangular decode, t < 36
    int tj = t - ti * (ti + 1) / 2;
    f32x4 acc[8][4] = {};
    ring4_gemm<8>((const char*)(Qb + ((size_t)b * SLEN + ti * 256) * ED), ED * 2,
                  (const char*)(Kb + ((size_t)b * SLEN + tj * 256) * ED), ED * 2,
                  32, smem, tid, acc);

    float* Sb = Sc + (size_t)b * SLEN * SLEN;
    int lane = tid & 63, wave = tid >> 6, wm = wave >> 2, wn = wave & 3;
    int rl = (lane >> 4) * 4, cl = lane & 15;
#pragma unroll
    for (int mf = 0; mf < 8; ++mf)
#pragma unroll
        for (int j = 0; j < 4; ++j) {
            int r = ti * 256 + wm * 128 + mf * 16 + rl + j;
#pragma unroll
            for (int nf = 0; nf < 4; ++nf) {
                int c = tj * 256 + wn * 64 + nf * 16 + cl;
                Sb[(size_t)r * SLEN + c] = acc[mf][nf][j] * 0.03125f;
            }
        }
}

// ---------------- causal row softmax; writes P (bf16) over the score row ----
__global__ __launch_bounds__(256) void softmax_rows(float* __restrict__ Sc)
{
    int q = blockIdx.x, b = blockIdx.y, tid = threadIdx.x;
    float* row = Sc + ((size_t)b * SLEN + q) * SLEN;
    int lane = tid & 63, wave = tid >> 6;
    __shared__ float red[4];

    float vals[8];
    float lmax = -3.0e38f;
#pragma unroll
    for (int r = 0; r < 2; ++r) {
        int i4 = tid + r * 256;
        float4 v = *(const float4*)(row + i4 * 4);
        vals[r * 4 + 0] = v.x; vals[r * 4 + 1] = v.y;
        vals[r * 4 + 2] = v.z; vals[r * 4 + 3] = v.w;
#pragma unroll
        for (int e = 0; e < 4; ++e) {
            int k = i4 * 4 + e;
            if (k <= q) lmax = fmaxf(lmax, vals[r * 4 + e]);
        }
    }
#pragma unroll
    for (int o = 32; o > 0; o >>= 1) lmax = fmaxf(lmax, __shfl_xor(lmax, o));
    if (lane == 0) red[wave] = lmax;
    __syncthreads();
    float m = fmaxf(fmaxf(red[0], red[1]), fmaxf(red[2], red[3]));
    __syncthreads();
    float lsum = 0.f;
#pragma unroll
    for (int r = 0; r < 2; ++r)
#pragma unroll
        for (int e = 0; e < 4; ++e) {
            int k = (tid + r * 256) * 4 + e;
            if (k <= q) lsum += __expf(vals[r * 4 + e] - m);
        }
#pragma unroll
    for (int o = 32; o > 0; o >>= 1) lsum += __shfl_xor(lsum, o);
    if (lane == 0) red[wave] = lsum;
    __syncthreads();
    float inv = 1.0f / (red[0] + red[1] + red[2] + red[3]);
    unsigned short* prow = (unsigned short*)row;
#pragma unroll
    for (int r = 0; r < 2; ++r) {
        int i4 = tid + r * 256;
        u16x4 o4;
#pragma unroll
        for (int e = 0; e < 4; ++e) {
            int k = i4 * 4 + e;
            float p = (k <= q) ? __expf(vals[r * 4 + e] - m) * inv : 0.0f;
            o4[e] = f2bf(p);
        }
        *(u16x4*)(prow + i4 * 4) = o4;
    }
}

// ---------------- O = P @ V (P bf16 ld 4096; Vt [b][d][s]); 128x256 tiles ----
__global__ __launch_bounds__(512, 2) void pv256(
    const bf16* __restrict__ P, const bf16* __restrict__ Vt, float* __restrict__ O)
{
    extern __shared__ char smem[];
    int mq = blockIdx.x, nd = blockIdx.y, b = blockIdx.z, tid = threadIdx.x;
    f32x4 acc[4][4] = {};
    int nkt = (mq + 1) * 4;                      // causal: k < (mq+1)*128
    ring4_gemm<4>((const char*)P + ((size_t)b * SLEN + mq * 128) * 8192, 8192,
                  (const char*)(Vt + ((size_t)b * ED + nd * 256) * SLEN), SLEN * 2,
                  nkt, smem, tid, acc);

    int lane = tid & 63, wave = tid >> 6, wm = wave >> 2, wn = wave & 3;
    int rl = (lane >> 4) * 4, cl = lane & 15;
    float* Ob = O + (size_t)b * SLEN * ED;
#pragma unroll
    for (int mf = 0; mf < 4; ++mf)
#pragma unroll
        for (int j = 0; j < 4; ++j) {
            int r = mq * 128 + wm * 64 + mf * 16 + rl + j;
#pragma unroll
            for (int nf = 0; nf < 4; ++nf) {
                int c = nd * 256 + wn * 64 + nf * 16 + cl;
                Ob[(size_t)r * ED + c] = acc[mf][nf][j];
            }
        }
}

extern "C" void kernel_launch(void* const* d_in, const int* in_sizes, int n_in,
                              void* d_out, int out_size, void* d_ws, size_t ws_size,
                              hipStream_t stream)
{
    const float* x  = (const float*)d_in[0];
    const float* wq = (const float*)d_in[1];
    const float* wk = (const float*)d_in[2];
    const float* wv = (const float*)d_in[3];
    float* out = (float*)d_out;

    char* ws = (char*)d_ws;
    bf16* xb  = (bf16*)(ws);                       // 16 MB
    bf16* wqb = (bf16*)(ws + 16777216);            // 2 MB
    bf16* wkb = (bf16*)(ws + 18874368);            // 2 MB
    bf16* wvb = (bf16*)(ws + 20971520);            // 2 MB
    bf16* Qb  = (bf16*)(ws + 23068672);            // 16 MB
    bf16* Kb  = (bf16*)(ws + 39845888);            // 16 MB
    bf16* Vt  = (bf16*)(ws + 56623104);            // 16 MB
    float* Sc = (float*)(ws + 73400320);           // 64 MB (P bf16 aliases this)

    // opt-in to >64KB dynamic LDS (immediate, not a stream op; capture-safe)
    (void)hipFuncSetAttribute((const void*)qkv256,
            hipFuncAttributeMaxDynamicSharedMemorySize, 131072);
    (void)hipFuncSetAttribute((const void*)qk256,
            hipFuncAttributeMaxDynamicSharedMemorySize, 131072);
    (void)hipFuncSetAttribute((const void*)pv256,
            hipFuncAttributeMaxDynamicSharedMemorySize, 98304);

    convert_to_bf16<<<5632, 256, 0, stream>>>(x, wq, wk, wv, xb, wqb, wkb, wvb);
    qkv256<<<384, 512, 131072, stream>>>(xb, wqb, wkb, wvb, Qb, Kb, Vt);
    qk256<<<dim3(36, NB), 512, 131072, stream>>>(Qb, Kb, Sc);
    softmax_rows<<<dim3(SLEN, NB), 256, 0, stream>>>(Sc);
    pv256<<<dim3(16, 4, NB), 512, 98304, stream>>>((const bf16*)Sc, Vt, out);
}

// Round 3
// 187.136 us; speedup vs baseline: 1.1114x; 1.0380x over previous
//
#include <hip/hip_runtime.h>
#include <hip/hip_bf16.h>
#include <stdint.h>

typedef __hip_bfloat16 bf16;
typedef __attribute__((ext_vector_type(8))) short bf16x8;
typedef __attribute__((ext_vector_type(4))) float f32x4;
typedef __attribute__((ext_vector_type(8))) unsigned short u16x8;
typedef __attribute__((ext_vector_type(4))) unsigned short u16x4;

#define SLEN 2048
#define ED   1024
#define NB   4

static __device__ __forceinline__ unsigned short f2bf(float f) {
    return __builtin_bit_cast(unsigned short, __float2bfloat16(f));
}

// ============================================================================
// 4-phase / BK=64 / 2-buffer GEMM core (m201-style schedule, plain HIP).
// 512 threads = 8 waves (2M x 4N). MFR = m-frags/wave (8 -> BM=256, 4 -> BM=128).
// BN = 256. LDS per buffer: A planes [kh][BM][32] + B planes [kh][256][32].
// Phase p: {ds_read subtile, stage 1 half-tile of tile T+1, [vmcnt], barrier,
//           lgkmcnt(0), setprio(1), MFMA cluster, setprio(0), barrier}.
// vmcnt(LA+LB) at end of P1 and P3 only (counted, never 0 in steady state).
// Safety: k-half kh1 of tile T first read at P2, covered by P1's vmcnt+barrier;
// kh0 of tile T+1 first read at next P0, covered by P3's vmcnt+barrier.
// Swizzle: 16B chunk c of a 64B half-row stored/read at c ^ ((row>>1)&3)
// (2-way = conflict-free); source pre-swizzled, LDS dest linear (rule 21).
// ============================================================================
template<int MFR>
__device__ __forceinline__ void gemm4p(
    const char* aT, int lda,      // A tile base, row stride (bytes)
    const char* bT, int ldb,      // B tile base (n-major, k contiguous)
    int nkt, char* sm, int tid, f32x4 (&acc)[MFR][4])
{
    constexpr int APL = MFR * 2048;           // A k-half plane bytes (BM*64)
    constexpr int BPL = 16384;                // B k-half plane bytes
    constexpr int BUF = 2 * APL + 2 * BPL;
    constexpr int LA  = MFR / 4;              // loads/thread per A half-plane
    const int lane = tid & 63, wave = tid >> 6;
    const int wm = wave >> 2, wn = wave & 3;
    const int fr = lane & 15, kc = lane >> 4;

    // stage unit u (0:A-kh0 1:B-kh0 2:A-kh1 3:B-kh1) of K-tile Tn
    auto STAGE = [&](int u, int Tn) {
        const int kh = u >> 1;
        const bool isB = u & 1;
        char* base = sm + (Tn & 1) * BUF + (isB ? 2 * APL + kh * BPL : kh * APL);
        const char* g = isB ? bT : aT;
        const int ld = isB ? ldb : lda;
        const int nl = isB ? 2 : LA;
#pragma unroll
        for (int j = 0; j < nl; ++j) {
            int rid = j * 512 + tid;
            int row = rid >> 2, c = rid & 3;
            const char* src = g + (size_t)row * ld + Tn * 128 + kh * 64
                            + ((c ^ ((row >> 1) & 3)) * 16);
            __builtin_amdgcn_global_load_lds(
                (const __attribute__((address_space(1))) uint32_t*)src,
                (__attribute__((address_space(3))) uint32_t*)(base + (j * 512 + wave * 64) * 16),
                16, 0, 0);
        }
    };
    auto RDA = [&](const char* As, int mh, int kh, bf16x8* a) {
#pragma unroll
        for (int i = 0; i < MFR / 2; ++i) {
            int row = wm * (MFR * 16) + (mh * (MFR / 2) + i) * 16 + fr;
            a[i] = *(const bf16x8*)(As + kh * APL + row * 64
                                    + ((kc ^ ((row >> 1) & 3)) * 16));
        }
    };
    auto RDB = [&](const char* Bs, int kh, bf16x8* b) {
#pragma unroll
        for (int nf = 0; nf < 4; ++nf) {
            int row = wn * 64 + nf * 16 + fr;
            b[nf] = *(const bf16x8*)(Bs + kh * BPL + row * 64
                                     + ((kc ^ ((row >> 1) & 3)) * 16));
        }
    };
    auto MM = [&](int mh, bf16x8* a, bf16x8* b) {
        __builtin_amdgcn_s_setprio(1);
#pragma unroll
        for (int i = 0; i < MFR / 2; ++i)
#pragma unroll
            for (int nf = 0; nf < 4; ++nf)
                acc[mh * (MFR / 2) + i][nf] = __builtin_amdgcn_mfma_f32_16x16x32_bf16(
                    a[i], b[nf], acc[mh * (MFR / 2) + i][nf], 0, 0, 0);
        __builtin_amdgcn_s_setprio(0);
    };
#define VM_N() do { if constexpr (MFR == 8) asm volatile("s_waitcnt vmcnt(4)" ::: "memory"); \
                    else                    asm volatile("s_waitcnt vmcnt(3)" ::: "memory"); } while (0)

    // prologue: stage tile 0 fully; wait until its kh0 halves landed
    STAGE(0, 0); STAGE(1, 0); STAGE(2, 0); STAGE(3, 0);
    VM_N();
    __builtin_amdgcn_s_barrier();

    for (int T = 0; T < nkt; ++T) {
        const char* buf = sm + (T & 1) * BUF;
        const char* As = buf;
        const char* Bs = buf + 2 * APL;
        const bool pre = (T + 1 < nkt);
        bf16x8 a[MFR / 2], b[4];

        // ---- P0: (mh0, kh0) ----
        RDA(As, 0, 0, a); RDB(Bs, 0, b);
        if (pre) STAGE(0, T + 1);
        __builtin_amdgcn_s_barrier();
        asm volatile("s_waitcnt lgkmcnt(0)" ::: "memory");
        MM(0, a, b);
        __builtin_amdgcn_s_barrier();
        // ---- P1: (mh1, kh0) ----
        RDA(As, 1, 0, a);
        if (pre) { STAGE(1, T + 1); VM_N(); }
        else     asm volatile("s_waitcnt vmcnt(0)" ::: "memory");
        __builtin_amdgcn_s_barrier();
        asm volatile("s_waitcnt lgkmcnt(0)" ::: "memory");
        MM(1, a, b);
        __builtin_amdgcn_s_barrier();
        // ---- P2: (mh0, kh1) ----
        RDA(As, 0, 1, a); RDB(Bs, 1, b);
        if (pre) STAGE(2, T + 1);
        __builtin_amdgcn_s_barrier();
        asm volatile("s_waitcnt lgkmcnt(0)" ::: "memory");
        MM(0, a, b);
        __builtin_amdgcn_s_barrier();
        // ---- P3: (mh1, kh1) ----
        RDA(As, 1, 1, a);
        if (pre) { STAGE(3, T + 1); VM_N(); }
        __builtin_amdgcn_s_barrier();
        asm volatile("s_waitcnt lgkmcnt(0)" ::: "memory");
        MM(1, a, b);
        __builtin_amdgcn_s_barrier();
    }
#undef VM_N
}

// ---------------- convert fp32 -> bf16 (x and the 3 weights) ----------------
__global__ __launch_bounds__(256) void convert_to_bf16(
    const float* __restrict__ x, const float* __restrict__ wq,
    const float* __restrict__ wk, const float* __restrict__ wv,
    bf16* __restrict__ xb, bf16* __restrict__ wqb,
    bf16* __restrict__ wkb, bf16* __restrict__ wvb)
{
    long g = (long)blockIdx.x * 256 + threadIdx.x;   // each thread: 8 elements
    const float* src; bf16* dst; long o;
    if (g < 1048576) { src = x; dst = xb; o = g * 8; }
    else {
        long g2 = g - 1048576;
        int w = (int)(g2 >> 17);
        o = (g2 & 131071) * 8;
        src = (w == 0) ? wq : (w == 1) ? wk : wv;
        dst = (w == 0) ? wqb : (w == 1) ? wkb : wvb;
    }
    float4 v0 = *(const float4*)(src + o);
    float4 v1 = *(const float4*)(src + o + 4);
    u16x8 r;
    r[0] = f2bf(v0.x); r[1] = f2bf(v0.y); r[2] = f2bf(v0.z); r[3] = f2bf(v0.w);
    r[4] = f2bf(v1.x); r[5] = f2bf(v1.y); r[6] = f2bf(v1.z); r[7] = f2bf(v1.w);
    *(u16x8*)(dst + o) = r;
}

// ---------------- fused QKV: [8192,3072] = xb @ [wq;wk;wv]^T, 128x256 tiles --
__global__ __launch_bounds__(512, 2) void qkv128(
    const bf16* __restrict__ xb, const bf16* __restrict__ wqb,
    const bf16* __restrict__ wkb, const bf16* __restrict__ wvb,
    bf16* __restrict__ Qb, bf16* __restrict__ Kb, bf16* __restrict__ Vt)
{
    extern __shared__ char smem[];
    int bid = blockIdx.x;
    int wg = (bid & 7) * 96 + (bid >> 3);        // XCD swizzle (768 = 8*96)
    int tm = wg / 12, tn = wg % 12;
    int tid = threadIdx.x;
    const bf16* W = (tn < 4) ? wqb : (tn < 8) ? wkb : wvb;
    int tnl = tn & 3;
    f32x4 acc[4][4] = {};
    gemm4p<4>((const char*)(xb + (size_t)tm * 128 * ED), ED * 2,
              (const char*)(W + (size_t)tnl * 256 * ED), ED * 2,
              16, smem, tid, acc);

    int lane = tid & 63, wave = tid >> 6, wm = wave >> 2, wn = wave & 3;
    int rl = (lane >> 4) * 4, cl = lane & 15;
    if (tn < 8) {
        bf16* C = (tn < 4) ? Qb : Kb;
#pragma unroll
        for (int mf = 0; mf < 4; ++mf)
#pragma unroll
            for (int j = 0; j < 4; ++j) {
                int r = tm * 128 + wm * 64 + mf * 16 + rl + j;
#pragma unroll
                for (int nf = 0; nf < 4; ++nf) {
                    int c = ((tn & 3) * 256 + wn * 64 + nf * 16 + cl);
                    C[(size_t)r * ED + c] = __float2bfloat16(acc[mf][nf][j]);
                }
            }
    } else {
#pragma unroll
        for (int mf = 0; mf < 4; ++mf)
#pragma unroll
            for (int j = 0; j < 4; ++j) {
                int r = tm * 128 + wm * 64 + mf * 16 + rl + j;
                int bb = r >> 11, s = r & 2047;
#pragma unroll
                for (int nf = 0; nf < 4; ++nf) {
                    int d = ((tn & 3) * 256 + wn * 64 + nf * 16 + cl);
                    Vt[(((size_t)bb << 10) + d) * SLEN + s] = __float2bfloat16(acc[mf][nf][j]);
                }
            }
    }
}

// ---------------- scores = Q @ K^T / 32, lower-tri 256^2 tiles only ----------
__global__ __launch_bounds__(512, 2) void qk256(
    const bf16* __restrict__ Qb, const bf16* __restrict__ Kb, float* __restrict__ Sc)
{
    extern __shared__ char smem[];
    int t = blockIdx.x, b = blockIdx.y, tid = threadIdx.x;
    int ti = 0;
    while ((ti + 1) * (ti + 2) / 2 <= t) ++ti;   // triangular decode, t < 36
    int tj = t - ti * (ti + 1) / 2;
    f32x4 acc[8][4] = {};
    gemm4p<8>((const char*)(Qb + ((size_t)b * SLEN + ti * 256) * ED), ED * 2,
              (const char*)(Kb + ((size_t)b * SLEN + tj * 256) * ED), ED * 2,
              16, smem, tid, acc);

    float* Sb = Sc + (size_t)b * SLEN * SLEN;
    int lane = tid & 63, wave = tid >> 6, wm = wave >> 2, wn = wave & 3;
    int rl = (lane >> 4) * 4, cl = lane & 15;
#pragma unroll
    for (int mf = 0; mf < 8; ++mf)
#pragma unroll
        for (int j = 0; j < 4; ++j) {
            int r = ti * 256 + wm * 128 + mf * 16 + rl + j;
#pragma unroll
            for (int nf = 0; nf < 4; ++nf) {
                int c = tj * 256 + wn * 64 + nf * 16 + cl;
                Sb[(size_t)r * SLEN + c] = acc[mf][nf][j] * 0.03125f;
            }
        }
}

// ---------------- causal row softmax; writes P (bf16) over the score row ----
__global__ __launch_bounds__(256) void softmax_rows(float* __restrict__ Sc)
{
    int q = blockIdx.x, b = blockIdx.y, tid = threadIdx.x;
    float* row = Sc + ((size_t)b * SLEN + q) * SLEN;
    int lane = tid & 63, wave = tid >> 6;
    __shared__ float red[4];

    float vals[8];
    float lmax = -3.0e38f;
#pragma unroll
    for (int r = 0; r < 2; ++r) {
        int i4 = tid + r * 256;
        float4 v = *(const float4*)(row + i4 * 4);
        vals[r * 4 + 0] = v.x; vals[r * 4 + 1] = v.y;
        vals[r * 4 + 2] = v.z; vals[r * 4 + 3] = v.w;
#pragma unroll
        for (int e = 0; e < 4; ++e) {
            int k = i4 * 4 + e;
            if (k <= q) lmax = fmaxf(lmax, vals[r * 4 + e]);
        }
    }
#pragma unroll
    for (int o = 32; o > 0; o >>= 1) lmax = fmaxf(lmax, __shfl_xor(lmax, o));
    if (lane == 0) red[wave] = lmax;
    __syncthreads();
    float m = fmaxf(fmaxf(red[0], red[1]), fmaxf(red[2], red[3]));
    __syncthreads();
    float lsum = 0.f;
#pragma unroll
    for (int r = 0; r < 2; ++r)
#pragma unroll
        for (int e = 0; e < 4; ++e) {
            int k = (tid + r * 256) * 4 + e;
            if (k <= q) lsum += __expf(vals[r * 4 + e] - m);
        }
#pragma unroll
    for (int o = 32; o > 0; o >>= 1) lsum += __shfl_xor(lsum, o);
    if (lane == 0) red[wave] = lsum;
    __syncthreads();
    float inv = 1.0f / (red[0] + red[1] + red[2] + red[3]);
    unsigned short* prow = (unsigned short*)row;
#pragma unroll
    for (int r = 0; r < 2; ++r) {
        int i4 = tid + r * 256;
        u16x4 o4;
#pragma unroll
        for (int e = 0; e < 4; ++e) {
            int k = i4 * 4 + e;
            float p = (k <= q) ? __expf(vals[r * 4 + e] - m) * inv : 0.0f;
            o4[e] = f2bf(p);
        }
        *(u16x4*)(prow + i4 * 4) = o4;
    }
}

// ---------------- O = P @ V (P bf16 ld 4096; Vt [b][d][s]); 128x256 tiles ----
__global__ __launch_bounds__(512, 2) void pv128(
    const bf16* __restrict__ P, const bf16* __restrict__ Vt, float* __restrict__ O)
{
    extern __shared__ char smem[];
    int mq = blockIdx.x, nd = blockIdx.y, b = blockIdx.z, tid = threadIdx.x;
    f32x4 acc[4][4] = {};
    int nkt = (mq + 1) * 2;                      // causal: k < (mq+1)*128
    gemm4p<4>((const char*)P + ((size_t)b * SLEN + mq * 128) * 8192, 8192,
              (const char*)(Vt + ((size_t)b * ED + nd * 256) * SLEN), SLEN * 2,
              nkt, smem, tid, acc);

    int lane = tid & 63, wave = tid >> 6, wm = wave >> 2, wn = wave & 3;
    int rl = (lane >> 4) * 4, cl = lane & 15;
    float* Ob = O + (size_t)b * SLEN * ED;
#pragma unroll
    for (int mf = 0; mf < 4; ++mf)
#pragma unroll
        for (int j = 0; j < 4; ++j) {
            int r = mq * 128 + wm * 64 + mf * 16 + rl + j;
#pragma unroll
            for (int nf = 0; nf < 4; ++nf) {
                int c = nd * 256 + wn * 64 + nf * 16 + cl;
                Ob[(size_t)r * ED + c] = acc[mf][nf][j];
            }
        }
}

extern "C" void kernel_launch(void* const* d_in, const int* in_sizes, int n_in,
                              void* d_out, int out_size, void* d_ws, size_t ws_size,
                              hipStream_t stream)
{
    const float* x  = (const float*)d_in[0];
    const float* wq = (const float*)d_in[1];
    const float* wk = (const float*)d_in[2];
    const float* wv = (const float*)d_in[3];
    float* out = (float*)d_out;

    char* ws = (char*)d_ws;
    bf16* xb  = (bf16*)(ws);                       // 16 MB
    bf16* wqb = (bf16*)(ws + 16777216);            // 2 MB
    bf16* wkb = (bf16*)(ws + 18874368);            // 2 MB
    bf16* wvb = (bf16*)(ws + 20971520);            // 2 MB
    bf16* Qb  = (bf16*)(ws + 23068672);            // 16 MB
    bf16* Kb  = (bf16*)(ws + 39845888);            // 16 MB
    bf16* Vt  = (bf16*)(ws + 56623104);            // 16 MB
    float* Sc = (float*)(ws + 73400320);           // 64 MB (P bf16 aliases this)

    (void)hipFuncSetAttribute((const void*)qkv128,
            hipFuncAttributeMaxDynamicSharedMemorySize, 98304);
    (void)hipFuncSetAttribute((const void*)qk256,
            hipFuncAttributeMaxDynamicSharedMemorySize, 131072);
    (void)hipFuncSetAttribute((const void*)pv128,
            hipFuncAttributeMaxDynamicSharedMemorySize, 98304);

    convert_to_bf16<<<5632, 256, 0, stream>>>(x, wq, wk, wv, xb, wqb, wkb, wvb);
    qkv128<<<768, 512, 98304, stream>>>(xb, wqb, wkb, wvb, Qb, Kb, Vt);
    qk256<<<dim3(36, NB), 512, 131072, stream>>>(Qb, Kb, Sc);
    softmax_rows<<<dim3(SLEN, NB), 256, 0, stream>>>(Sc);
    pv128<<<dim3(16, 4, NB), 512, 98304, stream>>>((const bf16*)Sc, Vt, out);
}

// Round 4
// 164.346 us; speedup vs baseline: 1.2655x; 1.1387x over previous
//
#include <hip/hip_runtime.h>
#include <hip/hip_bf16.h>
#include <stdint.h>

typedef __hip_bfloat16 bf16;
typedef __attribute__((ext_vector_type(8))) short bf16x8;
typedef __attribute__((ext_vector_type(4))) float f32x4;
typedef __attribute__((ext_vector_type(8))) unsigned short u16x8;
typedef __attribute__((ext_vector_type(4))) unsigned short u16x4;

#define SLEN 2048
#define ED   1024
#define NB   4
#define AS1 __attribute__((address_space(1)))
#define AS3 __attribute__((address_space(3)))

static __device__ __forceinline__ unsigned short f2bf(float f) {
    return __builtin_bit_cast(unsigned short, __float2bfloat16(f));
}

// ============================================================================
// 128x128 / BK=64 / 256-thread GEMM core. 4 waves (2M x 2N), wave tile 64x64.
// 2 phases per K-tile (kh0, kh1); 16 MFMA + 8 ds_read_b128 per phase per wave;
// ONE barrier per phase. 2-buffer LDS (64 KB) -> 2 blocks/CU for cross-block
// overlap. Counted vmcnt(4): phase kh stages unit kh of tile T+1; end-of-phase
// vmcnt(4) leaves exactly that unit outstanding, guaranteeing the unit needed
// by the NEXT phase has landed (vmcnt(0) only in the final tile).
// Overwrite safety: a write to plane (kh, buf) at tile T+1 is separated from
// the last read of that plane (tile T-1... tile T phase kh) by >=2 barriers
// plus the reader's own lgkmcnt(0) drain (wave-order analysis in journal).
// Swizzle (both-sides involution): 16B chunk c of a 64B half-row lives at
// c ^ ((row>>1)&3) -> 2-way bank aliasing only (free, m136); verified 0
// conflicts in R3.
// ============================================================================
__device__ __forceinline__ void gemm2p(
    const char* __restrict__ aT, int lda,   // A tile base, row stride bytes
    const char* __restrict__ bT, int ldb,   // B tile base (n-major, k contig)
    int nkt, char* sm, int tid, f32x4 (&acc)[4][4])
{
    const int lane = tid & 63, wave = tid >> 6;
    const int wm = wave >> 1, wn = wave & 1;
    const int fr = lane & 15, kc = lane >> 4;

    // stage k-half kh of K-tile Tn: A plane (8KB) + B plane (8KB), 4 loads/thr
    auto STAGE = [&](int kh, int Tn) {
        char* base = sm + (Tn & 1) * 32768 + kh * 8192;
#pragma unroll
        for (int half = 0; half < 2; ++half) {
            const char* g = half ? bT : aT;
            const int ld = half ? ldb : lda;
            char* pb = base + half * 16384;
#pragma unroll
            for (int j = 0; j < 2; ++j) {
                int rid = j * 256 + tid;
                int row = rid >> 2, c = rid & 3;
                const char* src = g + (size_t)row * ld + Tn * 128 + kh * 64
                                + ((c ^ ((row >> 1) & 3)) * 16);
                __builtin_amdgcn_global_load_lds(
                    (const AS1 uint32_t*)src,
                    (AS3 uint32_t*)(pb + (j * 256 + wave * 64) * 16),
                    16, 0, 0);
            }
        }
    };

    STAGE(0, 0); STAGE(1, 0);
    asm volatile("s_waitcnt vmcnt(4)" ::: "memory");
    __builtin_amdgcn_sched_barrier(0);
    __builtin_amdgcn_s_barrier();

    for (int T = 0; T < nkt; ++T) {
        const bool pre = (T + 1 < nkt);
#pragma unroll
        for (int kh = 0; kh < 2; ++kh) {
            const char* buf = sm + (T & 1) * 32768 + kh * 8192;
            bf16x8 a[4], b[4];
#pragma unroll
            for (int i = 0; i < 4; ++i) {
                int row = wm * 64 + i * 16 + fr;
                a[i] = *(const bf16x8*)(buf + row * 64 + ((kc ^ ((row >> 1) & 3)) * 16));
            }
#pragma unroll
            for (int i = 0; i < 4; ++i) {
                int row = wn * 64 + i * 16 + fr;
                b[i] = *(const bf16x8*)(buf + 16384 + row * 64 + ((kc ^ ((row >> 1) & 3)) * 16));
            }
            if (pre) {
                STAGE(kh, T + 1);
                asm volatile("s_waitcnt vmcnt(4)" ::: "memory");
            } else {
                asm volatile("s_waitcnt vmcnt(0)" ::: "memory");
            }
            __builtin_amdgcn_sched_barrier(0);
            __builtin_amdgcn_s_barrier();
            asm volatile("s_waitcnt lgkmcnt(0)" ::: "memory");
            __builtin_amdgcn_sched_barrier(0);
            __builtin_amdgcn_s_setprio(1);
#pragma unroll
            for (int i = 0; i < 4; ++i)
#pragma unroll
                for (int n = 0; n < 4; ++n)
                    acc[i][n] = __builtin_amdgcn_mfma_f32_16x16x32_bf16(
                        a[i], b[n], acc[i][n], 0, 0, 0);
            __builtin_amdgcn_s_setprio(0);
        }
    }
}

// ---------------- convert fp32 -> bf16 (x and the 3 weights) ----------------
__global__ __launch_bounds__(256) void convert_to_bf16(
    const float* __restrict__ x, const float* __restrict__ wq,
    const float* __restrict__ wk, const float* __restrict__ wv,
    bf16* __restrict__ xb, bf16* __restrict__ wqb,
    bf16* __restrict__ wkb, bf16* __restrict__ wvb)
{
    long g = (long)blockIdx.x * 256 + threadIdx.x;   // each thread: 8 elements
    const float* src; bf16* dst; long o;
    if (g < 1048576) { src = x; dst = xb; o = g * 8; }
    else {
        long g2 = g - 1048576;
        int w = (int)(g2 >> 17);
        o = (g2 & 131071) * 8;
        src = (w == 0) ? wq : (w == 1) ? wk : wv;
        dst = (w == 0) ? wqb : (w == 1) ? wkb : wvb;
    }
    float4 v0 = *(const float4*)(src + o);
    float4 v1 = *(const float4*)(src + o + 4);
    u16x8 r;
    r[0] = f2bf(v0.x); r[1] = f2bf(v0.y); r[2] = f2bf(v0.z); r[3] = f2bf(v0.w);
    r[4] = f2bf(v1.x); r[5] = f2bf(v1.y); r[6] = f2bf(v1.z); r[7] = f2bf(v1.w);
    *(u16x8*)(dst + o) = r;
}

// ---------------- fused QKV: [8192,3072] = xb @ [wq;wk;wv]^T ----------------
// 1536 blocks = 3 exact waves of 512 (2/CU). XCD swizzle: each XCD owns an
// 8-row tm slice (A = 2MB, L2-resident) and sweeps tn.
__global__ __launch_bounds__(256, 2) void qkv_gemm(
    const bf16* __restrict__ xb, const bf16* __restrict__ wqb,
    const bf16* __restrict__ wkb, const bf16* __restrict__ wvb,
    bf16* __restrict__ Qb, bf16* __restrict__ Kb, bf16* __restrict__ Vt)
{
    extern __shared__ char smem[];
    int bid = blockIdx.x, tid = threadIdx.x;
    int xcd = bid & 7, i = bid >> 3;            // i in 0..191
    int tm = (xcd << 3) | (i & 7);              // 0..63
    int tn = i >> 3;                            // 0..23
    const bf16* W = (tn < 8) ? wqb : (tn < 16) ? wkb : wvb;
    int tnl = tn & 7;
    f32x4 acc[4][4] = {};
    gemm2p((const char*)(xb + (size_t)tm * 128 * ED), ED * 2,
           (const char*)(W + (size_t)tnl * 128 * ED), ED * 2,
           16, smem, tid, acc);

    int lane = tid & 63, wave = tid >> 6, wm = wave >> 1, wn = wave & 1;
    int rl = (lane >> 4) * 4, cl = lane & 15;
    if (tn < 16) {
        bf16* C = (tn < 8) ? Qb : Kb;
#pragma unroll
        for (int mf = 0; mf < 4; ++mf)
#pragma unroll
            for (int j = 0; j < 4; ++j) {
                int r = tm * 128 + wm * 64 + mf * 16 + rl + j;
#pragma unroll
                for (int nf = 0; nf < 4; ++nf) {
                    int c = tnl * 128 + wn * 64 + nf * 16 + cl;
                    C[(size_t)r * ED + c] = __float2bfloat16(acc[mf][nf][j]);
                }
            }
    } else {
#pragma unroll
        for (int mf = 0; mf < 4; ++mf)
#pragma unroll
            for (int j = 0; j < 4; ++j) {
                int r = tm * 128 + wm * 64 + mf * 16 + rl + j;
                int bb = r >> 11, s = r & 2047;
#pragma unroll
                for (int nf = 0; nf < 4; ++nf) {
                    int d = tnl * 128 + wn * 64 + nf * 16 + cl;
                    Vt[(((size_t)bb << 10) + d) * SLEN + s] = __float2bfloat16(acc[mf][nf][j]);
                }
            }
    }
}

// ---------------- scores = Q @ K^T / 32, lower-tri 128^2 tiles --------------
// 136 tiles x 4 batches = 544 blocks, all K=1024 (perfect balance).
__global__ __launch_bounds__(256, 2) void qk_gemm(
    const bf16* __restrict__ Qb, const bf16* __restrict__ Kb, float* __restrict__ Sc)
{
    extern __shared__ char smem[];
    int bx = blockIdx.x, b = blockIdx.y, tid = threadIdx.x;
    int t = (bx & 7) * 17 + (bx >> 3);           // XCD swizzle, 136 = 8*17
    int ti = 0;
    while ((ti + 1) * (ti + 2) / 2 <= t) ++ti;   // triangular decode, ti<16
    int tj = t - ti * (ti + 1) / 2;
    f32x4 acc[4][4] = {};
    gemm2p((const char*)(Qb + ((size_t)b * SLEN + ti * 128) * ED), ED * 2,
           (const char*)(Kb + ((size_t)b * SLEN + tj * 128) * ED), ED * 2,
           16, smem, tid, acc);

    float* Sb = Sc + (size_t)b * SLEN * SLEN;
    int lane = tid & 63, wave = tid >> 6, wm = wave >> 1, wn = wave & 1;
    int rl = (lane >> 4) * 4, cl = lane & 15;
#pragma unroll
    for (int mf = 0; mf < 4; ++mf)
#pragma unroll
        for (int j = 0; j < 4; ++j) {
            int r = ti * 128 + wm * 64 + mf * 16 + rl + j;
#pragma unroll
            for (int nf = 0; nf < 4; ++nf) {
                int c = tj * 128 + wn * 64 + nf * 16 + cl;
                Sb[(size_t)r * SLEN + c] = acc[mf][nf][j] * 0.03125f;
            }
        }
}

// ---------------- causal row softmax; writes P (bf16) over the score row ----
__global__ __launch_bounds__(256) void softmax_rows(float* __restrict__ Sc)
{
    int q = blockIdx.x, b = blockIdx.y, tid = threadIdx.x;
    float* row = Sc + ((size_t)b * SLEN + q) * SLEN;
    int lane = tid & 63, wave = tid >> 6;
    __shared__ float red[4];

    float vals[8];
    float lmax = -3.0e38f;
#pragma unroll
    for (int r = 0; r < 2; ++r) {
        int i4 = tid + r * 256;
        float4 v = *(const float4*)(row + i4 * 4);
        vals[r * 4 + 0] = v.x; vals[r * 4 + 1] = v.y;
        vals[r * 4 + 2] = v.z; vals[r * 4 + 3] = v.w;
#pragma unroll
        for (int e = 0; e < 4; ++e) {
            int k = i4 * 4 + e;
            if (k <= q) lmax = fmaxf(lmax, vals[r * 4 + e]);
        }
    }
#pragma unroll
    for (int o = 32; o > 0; o >>= 1) lmax = fmaxf(lmax, __shfl_xor(lmax, o));
    if (lane == 0) red[wave] = lmax;
    __syncthreads();
    float m = fmaxf(fmaxf(red[0], red[1]), fmaxf(red[2], red[3]));
    __syncthreads();
    float lsum = 0.f;
#pragma unroll
    for (int r = 0; r < 2; ++r)
#pragma unroll
        for (int e = 0; e < 4; ++e) {
            int k = (tid + r * 256) * 4 + e;
            if (k <= q) lsum += __expf(vals[r * 4 + e] - m);
        }
#pragma unroll
    for (int o = 32; o > 0; o >>= 1) lsum += __shfl_xor(lsum, o);
    if (lane == 0) red[wave] = lsum;
    __syncthreads();
    float inv = 1.0f / (red[0] + red[1] + red[2] + red[3]);
    unsigned short* prow = (unsigned short*)row;
#pragma unroll
    for (int r = 0; r < 2; ++r) {
        int i4 = tid + r * 256;
        u16x4 o4;
#pragma unroll
        for (int e = 0; e < 4; ++e) {
            int k = i4 * 4 + e;
            float p = (k <= q) ? __expf(vals[r * 4 + e] - m) * inv : 0.0f;
            o4[e] = f2bf(p);
        }
        *(u16x4*)(prow + i4 * 4) = o4;
    }
}

// ---------------- O = P @ V (P bf16 ld 4096; Vt [b][d][s]) ------------------
// 512 blocks (2/CU); mq reversed so longest-K blocks dispatch first.
__global__ __launch_bounds__(256, 2) void pv_gemm(
    const bf16* __restrict__ P, const bf16* __restrict__ Vt, float* __restrict__ O)
{
    extern __shared__ char smem[];
    int mq = 15 - blockIdx.x, nd = blockIdx.y, b = blockIdx.z, tid = threadIdx.x;
    f32x4 acc[4][4] = {};
    int nkt = (mq + 1) * 2;                      // causal: k < (mq+1)*128
    gemm2p((const char*)P + ((size_t)b * SLEN + mq * 128) * 8192, 8192,
           (const char*)(Vt + ((size_t)b * ED + nd * 128) * SLEN), SLEN * 2,
           nkt, smem, tid, acc);

    int lane = tid & 63, wave = tid >> 6, wm = wave >> 1, wn = wave & 1;
    int rl = (lane >> 4) * 4, cl = lane & 15;
    float* Ob = O + (size_t)b * SLEN * ED;
#pragma unroll
    for (int mf = 0; mf < 4; ++mf)
#pragma unroll
        for (int j = 0; j < 4; ++j) {
            int r = mq * 128 + wm * 64 + mf * 16 + rl + j;
#pragma unroll
            for (int nf = 0; nf < 4; ++nf) {
                int c = nd * 128 + wn * 64 + nf * 16 + cl;
                Ob[(size_t)r * ED + c] = acc[mf][nf][j];
            }
        }
}

extern "C" void kernel_launch(void* const* d_in, const int* in_sizes, int n_in,
                              void* d_out, int out_size, void* d_ws, size_t ws_size,
                              hipStream_t stream)
{
    const float* x  = (const float*)d_in[0];
    const float* wq = (const float*)d_in[1];
    const float* wk = (const float*)d_in[2];
    const float* wv = (const float*)d_in[3];
    float* out = (float*)d_out;

    char* ws = (char*)d_ws;
    bf16* xb  = (bf16*)(ws);                       // 16 MB
    bf16* wqb = (bf16*)(ws + 16777216);            // 2 MB
    bf16* wkb = (bf16*)(ws + 18874368);            // 2 MB
    bf16* wvb = (bf16*)(ws + 20971520);            // 2 MB
    bf16* Qb  = (bf16*)(ws + 23068672);            // 16 MB
    bf16* Kb  = (bf16*)(ws + 39845888);            // 16 MB
    bf16* Vt  = (bf16*)(ws + 56623104);            // 16 MB
    float* Sc = (float*)(ws + 73400320);           // 64 MB (P bf16 aliases this)

    (void)hipFuncSetAttribute((const void*)qkv_gemm,
            hipFuncAttributeMaxDynamicSharedMemorySize, 65536);
    (void)hipFuncSetAttribute((const void*)qk_gemm,
            hipFuncAttributeMaxDynamicSharedMemorySize, 65536);
    (void)hipFuncSetAttribute((const void*)pv_gemm,
            hipFuncAttributeMaxDynamicSharedMemorySize, 65536);

    convert_to_bf16<<<5632, 256, 0, stream>>>(x, wq, wk, wv, xb, wqb, wkb, wvb);
    qkv_gemm<<<1536, 256, 65536, stream>>>(xb, wqb, wkb, wvb, Qb, Kb, Vt);
    qk_gemm<<<dim3(136, NB), 256, 65536, stream>>>(Qb, Kb, Sc);
    softmax_rows<<<dim3(SLEN, NB), 256, 0, stream>>>(Sc);
    pv_gemm<<<dim3(16, 8, NB), 256, 65536, stream>>>((const bf16*)Sc, Vt, out);
}